// Round 10
// baseline (154.397 us; speedup 1.0000x reference)
//
#include <hip/hip_runtime.h>
#include <math.h>

// ---------------- problem constants ----------------
#define NBLOCKS 2048              // one block per (b, i): one 512-pos j-row
#define THREADS 512               // 8 waves: (et 0..3) x (ph 0..1)
#define TILE 64
#define ITERS 8

typedef __attribute__((ext_vector_type(8)))  short  short8;   // MFMA A/B frag
typedef __attribute__((ext_vector_type(4)))  float  float4v;
typedef __attribute__((ext_vector_type(16))) float  float16;  // 32x32 C/D frag

// gfx950 packed f32x2 -> bf16x2 (RNE), single VALU instruction
__device__ __forceinline__ unsigned cvt_pk(float lo, float hi) {
    unsigned r;
    asm("v_cvt_pk_bf16_f32 %0, %1, %2" : "=v"(r) : "v"(lo), "v"(hi));
    return r;
}

// NOTE (R1/R2): v_pk_max_i16-as-relu produced NaN twice. Do NOT reintroduce.
// SESSION MODEL (R0-R9): the kernel family is LDS-INSTRUCTION-PIPE bound.
// R5's ~2200 LDS ops/block x ~9cyc x 2 blocks x 4 rounds ≈ 158k cyc ≈ the
// 144k measured; MfmaUtil 30% = 19us MFMA floor / 60us. Deleting VALU (R4),
// raising occupancy (R5), splitting gangs (R7), adding ILP (R8) all changed
// nothing because none touched the LDS stream; R9 ADDED LDS (w2l staging,
// 4.2M bank conflicts) and regressed.
// R10: eliminate the LDS inner loop. (a) R9-verified identity: a wave doing
// layer-1 for ALL 128 chs holds layer-2's B-frags in its own registers ->
// no ash exchange. (b) R4 lesson: feature VALU is free (overlapped) ->
// recompute features per iter, no fA table. (c) b2 folded into a K-slot
// seed MFMA -> no b2s reads. Remaining LDS: the 4-et 'red' partial exchange
// only (~48 clean scalar ops/iter-block). LDS/block ~2200 -> ~400.
// Cost: L1 MFMAs + relu-packs duplicated 4x across et-waves (+24 MFMA/iter
// ≈ 190cyc, buys ~1100 LDS cyc) -- a good trade.
__device__ __forceinline__ int kmap(int c, int jj) {
    return 32 * (c >> 2) + 16 * ((c >> 1) & 1) + 4 * (c & 1) + ((jj >> 2) << 3) + (jj & 3);
}

__global__ __launch_bounds__(512, 4)
void crpb_mfma8(const float* __restrict__ gq,   // (512,3)
                const float* __restrict__ gkv,  // (4,512,3)
                const float* __restrict__ W1,   // (3,128)
                const float* __restrict__ b1,   // (128,)
                const float* __restrict__ W2,   // (128,128)
                const float* __restrict__ b2,   // (128,)
                const float* __restrict__ W3,   // (128,4)
                const float* __restrict__ b3,   // (4,)
                float* __restrict__ out)        // (16,512,512)
{
    // ONLY shared memory: layer-3 partial exchange. [buf][et][o][pos] f32.
    __shared__ float red[2][4][4][64];          // 8 KB

    const int tid  = threadIdx.x;
    const int lane = tid & 63;
    const int w    = __builtin_amdgcn_readfirstlane(tid >> 6);  // 0..7
    const int l31  = lane & 31;
    const int lh   = lane >> 5;

    const int et = w & 3;           // this wave's 32 out-channel tile
    const int ph = w >> 2;          // position half of the 64-tile
    const int pofs = ph * 32 + l31;

    // persistent zero C-operand
    float16 z16;
    #pragma unroll
    for (int r = 0; r < 16; ++r) z16[r] = 0.0f;

    // ---- layer-1 A-frags for ALL 4 ch-tiles (W1 hi/lo + b1 folded) ----
    // lh0 slots: (w0h,w0l),(w0h,w1h),(w1l,w1h),(w2h,w2l)  <-> B: (f0h,f0h),(f0l,f1h),(f1h,f1l),(f2h,f2h)
    // lh1 slots: (w2h,b1h),(b1l,0),0,0                    <-> B: (f2l,1.0),(1.0,0),0,0
    short8 w1f[4];
    #pragma unroll
    for (int ct4 = 0; ct4 < 4; ++ct4) {
        const int ch = ct4 * 32 + l31;
        const float w0 = W1[ch], w1v = W1[128 + ch], w2v = W1[256 + ch], b1v = b1[ch];
        const float w0h = __uint_as_float(cvt_pk(w0, w0) << 16);
        const float w1h = __uint_as_float(cvt_pk(w1v, w1v) << 16);
        const float w2h = __uint_as_float(cvt_pk(w2v, w2v) << 16);
        const float b1h = __uint_as_float(cvt_pk(b1v, b1v) << 16);
        const float w0l = w0 - w0h, w1l = w1v - w1h, w2l_ = w2v - w2h, b1l = b1v - b1h;
        unsigned d[4];
        if (lh == 0) {
            d[0] = cvt_pk(w0h, w0l);
            d[1] = cvt_pk(w0h, w1h);
            d[2] = cvt_pk(w1l, w1h);
            d[3] = cvt_pk(w2h, w2l_);
        } else {
            d[0] = cvt_pk(w2h, b1h);
            d[1] = cvt_pk(b1l, 0.0f);
            d[2] = 0; d[3] = 0;
        }
        __builtin_memcpy(&w1f[ct4], d, 16);
    }

    // ---- W2^T A-frags for this wave's et (32 VGPRs) ----
    short8 a2f[8];
    {
        const int e = et * 32 + l31;
        #pragma unroll
        for (int ks = 0; ks < 8; ++ks) {
            const int c = 2 * ks + lh;
            unsigned t0[4];
            #pragma unroll
            for (int t = 0; t < 4; ++t) {
                const int d0 = kmap(c, 2 * t), d1 = d0 + 1;
                t0[t] = cvt_pk(W2[d0 * 128 + e], W2[d1 * 128 + e]);
            }
            __builtin_memcpy(&a2f[ks], t0, 16);
        }
    }

    // ---- b2 seed frags: acc = mfma(b2A, constB, 0) puts b2[e] in every col ----
    // A lane(row e) lh0: slots (b2h, b2l, 0...); B lane lh0: (1.0, 1.0, 0...).
    short8 b2aA, cstB;
    {
        const float b2v = b2[et * 32 + l31];
        const float b2h = __uint_as_float(cvt_pk(b2v, b2v) << 16);
        const float b2l = b2v - b2h;
        unsigned da[4] = {0, 0, 0, 0}, db[4] = {0, 0, 0, 0};
        if (lh == 0) {
            da[0] = cvt_pk(b2h, b2l);
            db[0] = cvt_pk(1.0f, 1.0f);
        }
        __builtin_memcpy(&b2aA, da, 16);
        __builtin_memcpy(&cstB, db, 16);
    }

    // ---- W3 A-frags: 2 frags cover this wave's et (8 VGPRs) ----
    short8 w3a[2];
    #pragma unroll
    for (int m2 = 0; m2 < 2; ++m2) {
        unsigned tt[4];
        #pragma unroll
        for (int t = 0; t < 4; ++t) {
            const int chl = ((2 * t) & 3) + 8 * ((2 * t) >> 2) + 4 * lh + 16 * m2;
            const int ch0 = et * 32 + chl, ch1 = ch0 + 1;
            const float lo = (l31 < 4) ? W3[ch0 * 4 + l31] : 0.0f;
            const float hi = (l31 < 4) ? W3[ch1 * 4 + l31] : 0.0f;
            tt[t] = cvt_pk(lo, hi);
        }
        __builtin_memcpy(&w3a[m2], tt, 16);
    }
    const float b3r = b3[w & 3];

    // block-constant: one j-row (b, i fixed)
    const int posblock = blockIdx.x * 512;
    const int bb = posblock >> 18;
    const int i  = (posblock >> 9) & 511;
    const float q0 = gq[i * 3 + 0], q1 = gq[i * 3 + 1], q2 = gq[i * 3 + 2];
    const float* kvrow = gkv + (size_t)(bb << 9) * 3;

    // NO setup barrier: no shared staging exists. Waves drift freely;
    // the only sync is the per-iter red handoff.

    for (int it = 0; it < ITERS; ++it) {
        const int buf = it & 1;
        const int jpos = it * TILE + pofs;

        // ---- features for this lane's position (R0-R3 math, bit-identical) ----
        const float* kp = kvrow + (size_t)jpos * 3;
        const float c0 = q0 - kp[0], c1 = q1 - kp[1], c2 = q2 - kp[2];
        const float f0 = copysignf(__logf(1.0f + fabsf(c0)), c0);
        const float f1 = copysignf(__logf(1.0f + fabsf(c1)), c1);
        const float f2 = copysignf(__logf(1.0f + fabsf(c2)), c2);
        const unsigned u0 = cvt_pk(f0, f0), u2 = cvt_pk(f2, f2);
        const float f0h = __uint_as_float(u0 << 16);
        const float f1h = __uint_as_float(cvt_pk(f1, f1) << 16);
        const float f2h = __uint_as_float(u2 << 16);
        const float f0l = f0 - f0h, f1l = f1 - f1h, f2l = f2 - f2h;
        unsigned d[4];
        if (lh == 0) {
            d[0] = u0;                    // (f0h, f0h)
            d[1] = cvt_pk(f0l, f1);       // (f0l, f1h)
            d[2] = cvt_pk(f1, f1l);       // (f1h, f1l)
            d[3] = u2;                    // (f2h, f2h)
        } else {
            d[0] = cvt_pk(f2l, 1.0f);     // (f2l, 1.0) <- picks up b1
            d[1] = cvt_pk(1.0f, 0.0f);
            d[2] = 0; d[3] = 0;
        }
        short8 bf; __builtin_memcpy(&bf, d, 16);

        // ---- fused L1 -> L2 via register identity; acc seeded with b2 ----
        __builtin_amdgcn_s_setprio(1);
        float16 acc = __builtin_amdgcn_mfma_f32_32x32x16_bf16(b2aA, cstB, z16, 0, 0, 0);
        #pragma unroll
        for (int ct4 = 0; ct4 < 4; ++ct4) {
            float16 c1r = __builtin_amdgcn_mfma_f32_32x32x16_bf16(w1f[ct4], bf, z16, 0, 0, 0);
            unsigned pk0[4], pk1[4];
            #pragma unroll
            for (int t = 0; t < 4; ++t) {
                pk0[t] = cvt_pk(fmaxf(c1r[2 * t], 0.f),     fmaxf(c1r[2 * t + 1], 0.f));
                pk1[t] = cvt_pk(fmaxf(c1r[8 + 2 * t], 0.f), fmaxf(c1r[8 + 2 * t + 1], 0.f));
            }
            short8 h0, h1;
            __builtin_memcpy(&h0, pk0, 16);
            __builtin_memcpy(&h1, pk1, 16);
            // identity: octet m of ch-tile ct4 == B-frag for ks = 2*ct4 + m
            acc = __builtin_amdgcn_mfma_f32_32x32x16_bf16(a2f[2 * ct4],     h0, acc, 0, 0, 0);
            acc = __builtin_amdgcn_mfma_f32_32x32x16_bf16(a2f[2 * ct4 + 1], h1, acc, 0, 0, 0);
        }

        // ---- relu + layer-3 partial for this et ----
        unsigned pa0[4], pa1[4];
        #pragma unroll
        for (int t = 0; t < 4; ++t) {
            pa0[t] = cvt_pk(fmaxf(acc[2 * t], 0.f),     fmaxf(acc[2 * t + 1], 0.f));
            pa1[t] = cvt_pk(fmaxf(acc[8 + 2 * t], 0.f), fmaxf(acc[8 + 2 * t + 1], 0.f));
        }
        short8 fa0, fa1;
        __builtin_memcpy(&fa0, pa0, 16); __builtin_memcpy(&fa1, pa1, 16);
        float16 p;
        p = __builtin_amdgcn_mfma_f32_32x32x16_bf16(w3a[0], fa0, z16, 0, 0, 0);
        p = __builtin_amdgcn_mfma_f32_32x32x16_bf16(w3a[1], fa1, p, 0, 0, 0);
        __builtin_amdgcn_s_setprio(0);

        // ---- red write: conflict-free scalar stores [et][o][pos] ----
        if (lh == 0) {
            #pragma unroll
            for (int o = 0; o < 4; ++o)
                red[buf][et][o][pofs] = p[o];
        }

        __syncthreads();   // single barrier/iter: fences red[buf]

        // ---- phase R: waves 0..3 sum the 4 et-partials, coalesced store ----
        if (w < 4) {
            const int o = w, pos = lane;
            const float v = b3r
                          + red[buf][0][o][pos]
                          + red[buf][1][o][pos]
                          + red[buf][2][o][pos]
                          + red[buf][3][o][pos];
            out[((size_t)((bb << 2) + o) << 18) + ((size_t)i << 9) + it * TILE + pos] = v;
        }
    }
}

extern "C" void kernel_launch(void* const* d_in, const int* in_sizes, int n_in,
                              void* d_out, int out_size, void* d_ws, size_t ws_size,
                              hipStream_t stream) {
    const float* gq  = (const float*)d_in[0];
    const float* gkv = (const float*)d_in[1];
    const float* W1  = (const float*)d_in[2];
    const float* b1  = (const float*)d_in[3];
    const float* W2  = (const float*)d_in[4];
    const float* b2  = (const float*)d_in[5];
    const float* W3  = (const float*)d_in[6];
    const float* b3  = (const float*)d_in[7];
    float* out = (float*)d_out;

    crpb_mfma8<<<NBLOCKS, THREADS, 0, stream>>>(gq, gkv, W1, b1, W2, b2, W3, b3, out);
}

// Round 11
// 122.569 us; speedup vs baseline: 1.2597x; 1.2597x over previous
//
#include <hip/hip_runtime.h>
#include <math.h>

// ---------------- problem constants ----------------
#define NBLOCKS 2048              // one block per (b, i): one 512-pos j-row
#define THREADS 512               // 8 waves: (ct 0..3) x (ph 0..1)  [R5 geometry]
#define TILE 64
#define ITERS 8
#define CH 512                    // ushorts per k'-chunk: 64 pos * 8

typedef __attribute__((ext_vector_type(8)))  short  short8;   // MFMA A/B frag
typedef __attribute__((ext_vector_type(4)))  float  float4v;
typedef __attribute__((ext_vector_type(4)))  unsigned uint4v;
typedef __attribute__((ext_vector_type(16))) float  float16;  // 32x32 C/D frag

// gfx950 packed f32x2 -> bf16x2 (RNE), single VALU instruction
__device__ __forceinline__ unsigned cvt_pk(float lo, float hi) {
    unsigned r;
    asm("v_cvt_pk_bf16_f32 %0, %1, %2" : "=v"(r) : "v"(lo), "v"(hi));
    return r;
}

// NOTE (R1/R2): v_pk_max_i16-as-relu produced NaN twice. Do NOT reintroduce.
// SESSION MODEL (R0-R10, corrected): per-SIMD MFMA = ~32cyc per 32x32 mfma
// (8cyc ubench figure is CU-aggregated). R5: MFMA floor 18.8us/CU (=MfmaUtil
// 32% x 60us), VALU 29us, combined issue ~81% -> the kernel is ISSUE-WORK
// bound, not stall-bound. R10 (4x duplicated VALU) hit 95% issue and
// regressed -> deleting instructions from R5's structure is the only lever.
// R11 = R5 + b2-seed MFMA (verified R10): kills 4 ds_read_b128 + ~16 reg
// copies per wave-iter, +1 MFMA on the less-loaded pipe, b2s staging gone.
__device__ __forceinline__ int kmap(int c, int jj) {
    return 32 * (c >> 2) + 16 * ((c >> 1) & 1) + 4 * (c & 1) + ((jj >> 2) << 3) + (jj & 3);
}

__global__ __launch_bounds__(512, 4)
void crpb_mfma8(const float* __restrict__ gq,   // (512,3)
                const float* __restrict__ gkv,  // (4,512,3)
                const float* __restrict__ W1,   // (3,128)
                const float* __restrict__ b1,   // (128,)
                const float* __restrict__ W2,   // (128,128)
                const float* __restrict__ b2,   // (128,)
                const float* __restrict__ W3,   // (128,4)
                const float* __restrict__ b3,   // (4,)
                float* __restrict__ out)        // (16,512,512)
{
    __shared__ __align__(16) unsigned short ash[2][16 * CH];   // 2 x 16 KB h1 tile
    __shared__ __align__(16) float red[2][4 * 4 * 64];         // 2 x 4 KB [ct][o][pos]
    // per-block feature table (one j-row), B-frag word layout.
    __shared__ __align__(16) unsigned fA[512][4];              // 8 KB
    __shared__ __align__(16) unsigned fB[512];                 // 2 KB

    const int tid  = threadIdx.x;
    const int lane = tid & 63;
    const int w    = __builtin_amdgcn_readfirstlane(tid >> 6);  // 0..7
    const int l31  = lane & 31;
    const int lh   = lane >> 5;

    // wave role: ch-tile ct (32 chs), pos-half ph
    const int ct = w & 3;
    const int ph = w >> 2;
    const int pofs = ph * 32 + l31;     // this lane's position within tile

    // persistent zero C-operand (layer-1 / layer-3 / b2-seed MFMAs)
    float16 z16;
    #pragma unroll
    for (int r = 0; r < 16; ++r) z16[r] = 0.0f;

    // ---- layer-1 A-frag for this wave's ch tile (W1 hi/lo + b1 folded) ----
    // lh0 slots: (w0h,w0l),(w0h,w1h),(w1l,w1h),(w2h,w2l)  <-> B: (f0h,f0h),(f0l,f1h),(f1h,f1l),(f2h,f2h)
    // lh1 slots: (w2h,b1h),(b1l,0),0,0                    <-> B: (f2l,1.0),(1.0,0),0,0
    short8 w1f;
    {
        const int ch = ct * 32 + l31;
        const float w0 = W1[ch], w1v = W1[128 + ch], w2v = W1[256 + ch], b1v = b1[ch];
        const float w0h = __uint_as_float(cvt_pk(w0, w0) << 16);
        const float w1h = __uint_as_float(cvt_pk(w1v, w1v) << 16);
        const float w2h = __uint_as_float(cvt_pk(w2v, w2v) << 16);
        const float b1h = __uint_as_float(cvt_pk(b1v, b1v) << 16);
        const float w0l = w0 - w0h, w1l = w1v - w1h, w2l = w2v - w2h, b1l = b1v - b1h;
        unsigned d[4];
        if (lh == 0) {
            d[0] = cvt_pk(w0h, w0l);
            d[1] = cvt_pk(w0h, w1h);
            d[2] = cvt_pk(w1l, w1h);
            d[3] = cvt_pk(w2h, w2l);
        } else {
            d[0] = cvt_pk(w2h, b1h);
            d[1] = cvt_pk(b1l, 0.0f);
            d[2] = 0; d[3] = 0;
        }
        __builtin_memcpy(&w1f, d, 16);
    }

    // ---- W2^T A-frags for this wave's 32 out-chs (32 VGPRs) ----
    short8 a2f[8];
    {
        const int e = ct * 32 + l31;
        #pragma unroll
        for (int ks = 0; ks < 8; ++ks) {
            const int c = 2 * ks + lh;
            unsigned t0[4];
            #pragma unroll
            for (int t = 0; t < 4; ++t) {
                const int d0 = kmap(c, 2 * t), d1 = d0 + 1;
                t0[t] = cvt_pk(W2[d0 * 128 + e], W2[d1 * 128 + e]);
            }
            __builtin_memcpy(&a2f[ks], t0, 16);
        }
    }

    // ---- b2 seed frags (R10-verified): acc = mfma(b2aA, cstB, 0) ----
    // A row e, lh0 k-slots (b2h, b2l); B col pos, lh0 k-slots (1.0, 1.0)
    // -> acc[e][pos] = b2h + b2l ~= b2[e] (b2l exact in f32, rounded to bf16).
    short8 b2aA, cstB;
    {
        const float b2v = b2[ct * 32 + l31];
        const float b2h = __uint_as_float(cvt_pk(b2v, b2v) << 16);
        const float b2l = b2v - b2h;
        unsigned da[4] = {0, 0, 0, 0}, db[4] = {0, 0, 0, 0};
        if (lh == 0) {
            da[0] = cvt_pk(b2h, b2l);
            db[0] = cvt_pk(1.0f, 1.0f);
        }
        __builtin_memcpy(&b2aA, da, 16);
        __builtin_memcpy(&cstB, db, 16);
    }

    // ---- W3 A-frags: 2 frags cover this wave's 32 chs (8 VGPRs) ----
    short8 w3a[2];
    #pragma unroll
    for (int m2 = 0; m2 < 2; ++m2) {
        unsigned tt[4];
        #pragma unroll
        for (int t = 0; t < 4; ++t) {
            const int chl = ((2 * t) & 3) + 8 * ((2 * t) >> 2) + 4 * lh + 16 * m2;
            const int ch0 = ct * 32 + chl, ch1 = ch0 + 1;
            const float lo = (l31 < 4) ? W3[ch0 * 4 + l31] : 0.0f;
            const float hi = (l31 < 4) ? W3[ch1 * 4 + l31] : 0.0f;
            tt[t] = cvt_pk(lo, hi);
        }
        __builtin_memcpy(&w3a[m2], tt, 16);
    }
    const float b3r = b3[w & 3];   // phase R: waves 0..3, o = w

    // block-constant: one j-row (b, i fixed)
    const int posblock = blockIdx.x * 512;
    const int bb = posblock >> 18;
    const int i  = (posblock >> 9) & 511;
    const float q0 = gq[i * 3 + 0], q1 = gq[i * 3 + 1], q2 = gq[i * 3 + 2];
    const float* kvrow = gkv + (size_t)(bb << 9) * 3;

    // ---- feature precompute: whole j-row, once per block (1 pos/thread) ----
    {
        const int jj = tid;
        const float k0 = kvrow[jj * 3 + 0], k1 = kvrow[jj * 3 + 1], k2 = kvrow[jj * 3 + 2];
        const float c0 = q0 - k0, c1 = q1 - k1, c2 = q2 - k2;
        const float f0 = copysignf(__logf(1.0f + fabsf(c0)), c0);
        const float f1 = copysignf(__logf(1.0f + fabsf(c1)), c1);
        const float f2 = copysignf(__logf(1.0f + fabsf(c2)), c2);
        const unsigned u0 = cvt_pk(f0, f0), u2 = cvt_pk(f2, f2);
        const float f0h = __uint_as_float(u0 << 16);
        const float f1h = __uint_as_float(cvt_pk(f1, f1) << 16);
        const float f2h = __uint_as_float(u2 << 16);
        const float f0l = f0 - f0h, f1l = f1 - f1h, f2l = f2 - f2h;
        fA[jj][0] = u0;                    // (f0h, f0h)
        fA[jj][1] = cvt_pk(f0l, f1);       // (f0l, f1h)
        fA[jj][2] = cvt_pk(f1, f1l);       // (f1h, f1l)
        fA[jj][3] = u2;                    // (f2h, f2h)
        fB[jj]    = cvt_pk(f2l, 1.0f);     // (f2l, 1.0) ; word1 is const
    }
    __syncthreads();   // features visible to all waves

    // ======== phase A: B-frag from LDS -> layer-1 MFMA -> ash[buf] ========
    auto phaseA = [&](int x, int buf) {
        const int jpos = x * TILE + pofs;
        unsigned d[4];
        if (lh == 0) {
            const uint4v t = *(const uint4v*)&fA[jpos][0];
            d[0] = t[0]; d[1] = t[1]; d[2] = t[2]; d[3] = t[3];
        } else {
            d[0] = fB[jpos];
            d[1] = 0x00003F80u;            // (bf16 1.0, 0) <- picks up b1
            d[2] = 0; d[3] = 0;
        }
        short8 bf; __builtin_memcpy(&bf, d, 16);

        float16 c1r = __builtin_amdgcn_mfma_f32_32x32x16_bf16(w1f, bf, z16, 0, 0, 0);
        unsigned pk0[4], pk1[4];
        #pragma unroll
        for (int t = 0; t < 4; ++t) {
            pk0[t] = cvt_pk(fmaxf(c1r[2 * t], 0.f),     fmaxf(c1r[2 * t + 1], 0.f));
            pk1[t] = cvt_pk(fmaxf(c1r[8 + 2 * t], 0.f), fmaxf(c1r[8 + 2 * t + 1], 0.f));
        }
        short8 v0, v1;
        __builtin_memcpy(&v0, pk0, 16);
        __builtin_memcpy(&v1, pk1, 16);
        *(short8*)&ash[buf][(4 * ct + lh) * CH + pofs * 8]     = v0;   // m=0 octet
        *(short8*)&ash[buf][(4 * ct + 2 + lh) * CH + pofs * 8] = v1;   // m=1 octet
    };

    phaseA(0, 0);
    __syncthreads();   // fences ash[0]

    for (int it = 0; it < ITERS; ++it) {
        const int buf = it & 1;
        const int jb = it * TILE;

        // ======== phase B: acc seeded by b2-MFMA; 8 B-reads feed 8 MFMAs ========
        const unsigned short* br = &ash[buf][lh * CH + pofs * 8];

        // T5: boost issue priority through the dense MFMA region (R3: -2.7%).
        __builtin_amdgcn_s_setprio(1);
        float16 acc = __builtin_amdgcn_mfma_f32_32x32x16_bf16(b2aA, cstB, z16, 0, 0, 0);
        #pragma unroll
        for (int ks = 0; ks < 8; ++ks) {
            short8 bfrag = *(const short8*)(br + ks * 2 * CH);
            acc = __builtin_amdgcn_mfma_f32_32x32x16_bf16(a2f[ks], bfrag, acc, 0, 0, 0);
        }

        // ======== phase C': in-register relu + layer-3 (2 MFMAs over 32 chs) ========
        {
            unsigned pa0[4], pa1[4];
            #pragma unroll
            for (int t = 0; t < 4; ++t) {
                pa0[t] = cvt_pk(fmaxf(acc[2 * t], 0.f),     fmaxf(acc[2 * t + 1], 0.f));
                pa1[t] = cvt_pk(fmaxf(acc[8 + 2 * t], 0.f), fmaxf(acc[8 + 2 * t + 1], 0.f));
            }
            short8 fa0, fa1;
            __builtin_memcpy(&fa0, pa0, 16); __builtin_memcpy(&fa1, pa1, 16);
            float16 p;
            p = __builtin_amdgcn_mfma_f32_32x32x16_bf16(w3a[0], fa0, z16, 0, 0, 0);
            p = __builtin_amdgcn_mfma_f32_32x32x16_bf16(w3a[1], fa1, p, 0, 0, 0);
            __builtin_amdgcn_s_setprio(0);
            if (lh == 0) {
                #pragma unroll
                for (int o = 0; o < 4; ++o)
                    red[buf][ct * 256 + o * 64 + pofs] = p[o];
            }
        }

        // ======== phase A for next tile (other ash buffer) ========
        if (it != ITERS - 1) phaseA(it + 1, 1 - buf);

        __syncthreads();   // single barrier/tile: fences ash[1-buf] and red[buf]

        // ======== phase R: sum 4 ct-partials + b3, coalesced store (waves 0..3) ========
        if (w < 4) {
            const int o = w, pos = lane;
            const float v = b3r
                          + red[buf][0 * 256 + o * 64 + pos]
                          + red[buf][1 * 256 + o * 64 + pos]
                          + red[buf][2 * 256 + o * 64 + pos]
                          + red[buf][3 * 256 + o * 64 + pos];
            out[((size_t)((bb << 2) + o) << 18) + ((size_t)i << 9) + jb + pos] = v;
        }
    }
}

extern "C" void kernel_launch(void* const* d_in, const int* in_sizes, int n_in,
                              void* d_out, int out_size, void* d_ws, size_t ws_size,
                              hipStream_t stream) {
    const float* gq  = (const float*)d_in[0];
    const float* gkv = (const float*)d_in[1];
    const float* W1  = (const float*)d_in[2];
    const float* b1  = (const float*)d_in[3];
    const float* W2  = (const float*)d_in[4];
    const float* b2  = (const float*)d_in[5];
    const float* W3  = (const float*)d_in[6];
    const float* b3  = (const float*)d_in[7];
    float* out = (float*)d_out;

    crpb_mfma8<<<NBLOCKS, THREADS, 0, stream>>>(gq, gkv, W1, b1, W2, b2, W3, b3, out);
}

// Round 12
// 121.165 us; speedup vs baseline: 1.2743x; 1.0116x over previous
//
#include <hip/hip_runtime.h>
#include <math.h>

// ---------------- problem constants ----------------
#define NBLOCKS 2048              // one block per (b, i): one 512-pos j-row
#define THREADS 512               // 8 waves: (ct 0..3) x (ph 0..1)  [R5 geometry]
#define TILE 64
#define ITERS 8
#define CH 512                    // ushorts per k'-chunk: 64 pos * 8

typedef __attribute__((ext_vector_type(8)))  short  short8;   // MFMA A/B frag
typedef __attribute__((ext_vector_type(4)))  float  float4v;
typedef __attribute__((ext_vector_type(4)))  unsigned uint4v;
typedef __attribute__((ext_vector_type(16))) float  float16;  // 32x32 C/D frag

// gfx950 packed f32x2 -> bf16x2 (RNE), single VALU instruction
__device__ __forceinline__ unsigned cvt_pk(float lo, float hi) {
    unsigned r;
    asm("v_cvt_pk_bf16_f32 %0, %1, %2" : "=v"(r) : "v"(lo), "v"(hi));
    return r;
}

// NOTE (R1/R2): v_pk_max_i16-as-relu produced NaN twice. Do NOT reintroduce.
// NOTE (R11): b2-seed MFMA dropped occupancy 51->37 (AGPR liveness, not reg
// count) and regressed; reverted.
// SESSION MODEL (R0-R11, final form): VALUBusy INCLUDES MFMA cycles
// (R5: 49-32=17% pure VALU ~= hand count). The binding pipe is LDS:
// R5 = 222 LDS cyc/wave-iter (ash reads 96 + b2s 48 + ash writes 24 +
// fA 18 + red 36) x 64 wave-iters x 8 blocks/CU ~= 47us of the 60us wall
// (~79% busy). Explains all nulls: R4/R5/R7/R8 never touched the LDS
// stream; R9 added to it. ash reads are irreducible (pack-once/read-4x
// beats R10's pack-4x). b2s reads (48 cyc, 22%) are the removable item.
// R12 = R5 + b2 via SGPRs (readfirstlane) + lh-select acc init on the
// cold VALU pipe. Zero nominal VGPR cost; no MFMA-liveness change.
__device__ __forceinline__ int kmap(int c, int jj) {
    return 32 * (c >> 2) + 16 * ((c >> 1) & 1) + 4 * (c & 1) + ((jj >> 2) << 3) + (jj & 3);
}

__global__ __launch_bounds__(512, 4)
void crpb_mfma8(const float* __restrict__ gq,   // (512,3)
                const float* __restrict__ gkv,  // (4,512,3)
                const float* __restrict__ W1,   // (3,128)
                const float* __restrict__ b1,   // (128,)
                const float* __restrict__ W2,   // (128,128)
                const float* __restrict__ b2,   // (128,)
                const float* __restrict__ W3,   // (128,4)
                const float* __restrict__ b3,   // (4,)
                float* __restrict__ out)        // (16,512,512)
{
    __shared__ __align__(16) unsigned short ash[2][16 * CH];   // 2 x 16 KB h1 tile
    __shared__ __align__(16) float red[2][4 * 4 * 64];         // 2 x 4 KB [ct][o][pos]
    // per-block feature table (one j-row), B-frag word layout.
    __shared__ __align__(16) unsigned fA[512][4];              // 8 KB
    __shared__ __align__(16) unsigned fB[512];                 // 2 KB

    const int tid  = threadIdx.x;
    const int lane = tid & 63;
    const int w    = __builtin_amdgcn_readfirstlane(tid >> 6);  // 0..7
    const int l31  = lane & 31;
    const int lh   = lane >> 5;

    // wave role: ch-tile ct (32 chs), pos-half ph
    const int ct = w & 3;
    const int ph = w >> 2;
    const int pofs = ph * 32 + l31;     // this lane's position within tile

    // persistent zero C-operand (layer-1 and layer-3 MFMAs)
    float16 z16;
    #pragma unroll
    for (int r = 0; r < 16; ++r) z16[r] = 0.0f;

    // ---- layer-1 A-frag for this wave's ch tile (W1 hi/lo + b1 folded) ----
    // lh0 slots: (w0h,w0l),(w0h,w1h),(w1l,w1h),(w2h,w2l)  <-> B: (f0h,f0h),(f0l,f1h),(f1h,f1l),(f2h,f2h)
    // lh1 slots: (w2h,b1h),(b1l,0),0,0                    <-> B: (f2l,1.0),(1.0,0),0,0
    short8 w1f;
    {
        const int ch = ct * 32 + l31;
        const float w0 = W1[ch], w1v = W1[128 + ch], w2v = W1[256 + ch], b1v = b1[ch];
        const float w0h = __uint_as_float(cvt_pk(w0, w0) << 16);
        const float w1h = __uint_as_float(cvt_pk(w1v, w1v) << 16);
        const float w2h = __uint_as_float(cvt_pk(w2v, w2v) << 16);
        const float b1h = __uint_as_float(cvt_pk(b1v, b1v) << 16);
        const float w0l = w0 - w0h, w1l = w1v - w1h, w2l = w2v - w2h, b1l = b1v - b1h;
        unsigned d[4];
        if (lh == 0) {
            d[0] = cvt_pk(w0h, w0l);
            d[1] = cvt_pk(w0h, w1h);
            d[2] = cvt_pk(w1l, w1h);
            d[3] = cvt_pk(w2h, w2l);
        } else {
            d[0] = cvt_pk(w2h, b1h);
            d[1] = cvt_pk(b1l, 0.0f);
            d[2] = 0; d[3] = 0;
        }
        __builtin_memcpy(&w1f, d, 16);
    }

    // ---- W2^T A-frags for this wave's 32 out-chs (32 VGPRs) ----
    short8 a2f[8];
    {
        const int e = ct * 32 + l31;
        #pragma unroll
        for (int ks = 0; ks < 8; ++ks) {
            const int c = 2 * ks + lh;
            unsigned t0[4];
            #pragma unroll
            for (int t = 0; t < 4; ++t) {
                const int d0 = kmap(c, 2 * t), d1 = d0 + 1;
                t0[t] = cvt_pk(W2[d0 * 128 + e], W2[d1 * 128 + e]);
            }
            __builtin_memcpy(&a2f[ks], t0, 16);
        }
    }

    // ---- b2 in SGPRs (R12): 32 wave-uniform words for this ct ----
    // acc row = t + 8*qr + 4*lh, so lane-half selects between sb2[idx]
    // and sb2[idx+4] at acc init (VALU, compile-time indices only).
    unsigned sb2[32];
    #pragma unroll
    for (int k = 0; k < 32; ++k)
        sb2[k] = __builtin_amdgcn_readfirstlane(__float_as_uint(b2[ct * 32 + k]));

    // ---- W3 A-frags: 2 frags cover this wave's 32 chs (8 VGPRs) ----
    short8 w3a[2];
    #pragma unroll
    for (int m2 = 0; m2 < 2; ++m2) {
        unsigned tt[4];
        #pragma unroll
        for (int t = 0; t < 4; ++t) {
            const int chl = ((2 * t) & 3) + 8 * ((2 * t) >> 2) + 4 * lh + 16 * m2;
            const int ch0 = ct * 32 + chl, ch1 = ch0 + 1;
            const float lo = (l31 < 4) ? W3[ch0 * 4 + l31] : 0.0f;
            const float hi = (l31 < 4) ? W3[ch1 * 4 + l31] : 0.0f;
            tt[t] = cvt_pk(lo, hi);
        }
        __builtin_memcpy(&w3a[m2], tt, 16);
    }
    const float b3r = b3[w & 3];   // phase R: waves 0..3, o = w

    // block-constant: one j-row (b, i fixed)
    const int posblock = blockIdx.x * 512;
    const int bb = posblock >> 18;
    const int i  = (posblock >> 9) & 511;
    const float q0 = gq[i * 3 + 0], q1 = gq[i * 3 + 1], q2 = gq[i * 3 + 2];
    const float* kvrow = gkv + (size_t)(bb << 9) * 3;

    // ---- feature precompute: whole j-row, once per block (1 pos/thread) ----
    {
        const int jj = tid;
        const float k0 = kvrow[jj * 3 + 0], k1 = kvrow[jj * 3 + 1], k2 = kvrow[jj * 3 + 2];
        const float c0 = q0 - k0, c1 = q1 - k1, c2 = q2 - k2;
        const float f0 = copysignf(__logf(1.0f + fabsf(c0)), c0);
        const float f1 = copysignf(__logf(1.0f + fabsf(c1)), c1);
        const float f2 = copysignf(__logf(1.0f + fabsf(c2)), c2);
        const unsigned u0 = cvt_pk(f0, f0), u2 = cvt_pk(f2, f2);
        const float f0h = __uint_as_float(u0 << 16);
        const float f1h = __uint_as_float(cvt_pk(f1, f1) << 16);
        const float f2h = __uint_as_float(u2 << 16);
        const float f0l = f0 - f0h, f1l = f1 - f1h, f2l = f2 - f2h;
        fA[jj][0] = u0;                    // (f0h, f0h)
        fA[jj][1] = cvt_pk(f0l, f1);       // (f0l, f1h)
        fA[jj][2] = cvt_pk(f1, f1l);       // (f1h, f1l)
        fA[jj][3] = u2;                    // (f2h, f2h)
        fB[jj]    = cvt_pk(f2l, 1.0f);     // (f2l, 1.0) ; word1 is const
    }
    __syncthreads();   // features visible to all waves

    // ======== phase A: B-frag from LDS -> layer-1 MFMA -> ash[buf] ========
    auto phaseA = [&](int x, int buf) {
        const int jpos = x * TILE + pofs;
        unsigned d[4];
        if (lh == 0) {
            const uint4v t = *(const uint4v*)&fA[jpos][0];
            d[0] = t[0]; d[1] = t[1]; d[2] = t[2]; d[3] = t[3];
        } else {
            d[0] = fB[jpos];
            d[1] = 0x00003F80u;            // (bf16 1.0, 0) <- picks up b1
            d[2] = 0; d[3] = 0;
        }
        short8 bf; __builtin_memcpy(&bf, d, 16);

        float16 c1r = __builtin_amdgcn_mfma_f32_32x32x16_bf16(w1f, bf, z16, 0, 0, 0);
        unsigned pk0[4], pk1[4];
        #pragma unroll
        for (int t = 0; t < 4; ++t) {
            pk0[t] = cvt_pk(fmaxf(c1r[2 * t], 0.f),     fmaxf(c1r[2 * t + 1], 0.f));
            pk1[t] = cvt_pk(fmaxf(c1r[8 + 2 * t], 0.f), fmaxf(c1r[8 + 2 * t + 1], 0.f));
        }
        short8 v0, v1;
        __builtin_memcpy(&v0, pk0, 16);
        __builtin_memcpy(&v1, pk1, 16);
        *(short8*)&ash[buf][(4 * ct + lh) * CH + pofs * 8]     = v0;   // m=0 octet
        *(short8*)&ash[buf][(4 * ct + 2 + lh) * CH + pofs * 8] = v1;   // m=1 octet
    };

    phaseA(0, 0);
    __syncthreads();   // fences ash[0]

    for (int it = 0; it < ITERS; ++it) {
        const int buf = it & 1;
        const int jb = it * TILE;

        // ======== phase B: acc init from SGPR b2 (VALU, no LDS) ========
        float16 acc;
        #pragma unroll
        for (int qr = 0; qr < 4; ++qr) {
            #pragma unroll
            for (int t = 0; t < 4; ++t) {
                const unsigned lo = sb2[8 * qr + t];
                const unsigned hi = sb2[8 * qr + t + 4];
                acc[4 * qr + t] = __uint_as_float(lh ? hi : lo);
            }
        }
        const unsigned short* br = &ash[buf][lh * CH + pofs * 8];

        // T5: boost issue priority through the dense MFMA region (R3: -2.7%).
        __builtin_amdgcn_s_setprio(1);
        #pragma unroll
        for (int ks = 0; ks < 8; ++ks) {
            short8 bfrag = *(const short8*)(br + ks * 2 * CH);
            acc = __builtin_amdgcn_mfma_f32_32x32x16_bf16(a2f[ks], bfrag, acc, 0, 0, 0);
        }

        // ======== phase C': in-register relu + layer-3 (2 MFMAs over 32 chs) ========
        {
            unsigned pa0[4], pa1[4];
            #pragma unroll
            for (int t = 0; t < 4; ++t) {
                pa0[t] = cvt_pk(fmaxf(acc[2 * t], 0.f),     fmaxf(acc[2 * t + 1], 0.f));
                pa1[t] = cvt_pk(fmaxf(acc[8 + 2 * t], 0.f), fmaxf(acc[8 + 2 * t + 1], 0.f));
            }
            short8 fa0, fa1;
            __builtin_memcpy(&fa0, pa0, 16); __builtin_memcpy(&fa1, pa1, 16);
            float16 p;
            p = __builtin_amdgcn_mfma_f32_32x32x16_bf16(w3a[0], fa0, z16, 0, 0, 0);
            p = __builtin_amdgcn_mfma_f32_32x32x16_bf16(w3a[1], fa1, p, 0, 0, 0);
            __builtin_amdgcn_s_setprio(0);
            if (lh == 0) {
                #pragma unroll
                for (int o = 0; o < 4; ++o)
                    red[buf][ct * 256 + o * 64 + pofs] = p[o];
            }
        }

        // ======== phase A for next tile (other ash buffer) ========
        if (it != ITERS - 1) phaseA(it + 1, 1 - buf);

        __syncthreads();   // single barrier/tile: fences ash[1-buf] and red[buf]

        // ======== phase R: sum 4 ct-partials + b3, coalesced store (waves 0..3) ========
        if (w < 4) {
            const int o = w, pos = lane;
            const float v = b3r
                          + red[buf][0 * 256 + o * 64 + pos]
                          + red[buf][1 * 256 + o * 64 + pos]
                          + red[buf][2 * 256 + o * 64 + pos]
                          + red[buf][3 * 256 + o * 64 + pos];
            out[((size_t)((bb << 2) + o) << 18) + ((size_t)i << 9) + jb + pos] = v;
        }
    }
}

extern "C" void kernel_launch(void* const* d_in, const int* in_sizes, int n_in,
                              void* d_out, int out_size, void* d_ws, size_t ws_size,
                              hipStream_t stream) {
    const float* gq  = (const float*)d_in[0];
    const float* gkv = (const float*)d_in[1];
    const float* W1  = (const float*)d_in[2];
    const float* b1  = (const float*)d_in[3];
    const float* W2  = (const float*)d_in[4];
    const float* b2  = (const float*)d_in[5];
    const float* W3  = (const float*)d_in[6];
    const float* b3  = (const float*)d_in[7];
    float* out = (float*)d_out;

    crpb_mfma8<<<NBLOCKS, THREADS, 0, stream>>>(gq, gkv, W1, b1, W2, b2, W3, b3, out);
}

// Round 13
// 118.705 us; speedup vs baseline: 1.3007x; 1.0207x over previous
//
#include <hip/hip_runtime.h>
#include <math.h>

// ---------------- problem constants ----------------
#define NBLOCKS 2048              // one block per (b, i): one 512-pos j-row
#define THREADS 512               // 8 waves: (ct 0..3) x (ph 0..1)
#define TILE 64
#define ITERS 8
#define CH 512                    // ushorts per k'-chunk: 64 pos * 8

typedef __attribute__((ext_vector_type(8)))  short  short8;   // MFMA A/B frag
typedef __attribute__((ext_vector_type(4)))  float  float4v;
typedef __attribute__((ext_vector_type(4)))  unsigned uint4v;
typedef __attribute__((ext_vector_type(16))) float  float16;  // 32x32 C/D frag

// gfx950 packed f32x2 -> bf16x2 (RNE), single VALU instruction
__device__ __forceinline__ unsigned cvt_pk(float lo, float hi) {
    unsigned r;
    asm("v_cvt_pk_bf16_f32 %0, %1, %2" : "=v"(r) : "v"(lo), "v"(hi));
    return r;
}

// ===================== SESSION LEDGER (R0-R12) =====================
// BEST = THIS KERNEL (R5): dispatch ~60us, bench 118.85us, occ 51%.
// Hard constraints measured on MI355X:
//  * REG CLIFF: at 512thr, total unified VGPR+AGPR <=128/wave -> 4
//    waves/SIMD (occ 51%); ONE reg over -> 3 waves/SIMD (occ 37%,
//    +4us). This kernel sits exactly at the boundary (arch VGPR 40).
//    Confirmed 3x: R6 (+32r), R11 (+8r), R12 (+16r hoisted) all -> 37%.
//  * LDS PIPE is the binding pipe: ~222 cyc/wave-iter (ash reads 96,
//    b2s 48, ash writes 24, fA 18, red 36) ~= 47us of the 60us wall.
//    But every LDS-reduction costs regs (cliff) or duplicated compute
//    (R10: 4x VALU -> 95% issue, 100us).
//  * VALUBusy INCLUDES MFMA cycles (49% = 32% MFMA + ~17% pure VALU).
//  * MFMA floor 19us (11 mfma x ~32cyc/SIMD x 8 iters x 4 waves x 4
//    rounds); HBM 3% (irrelevant).
// Falsified alternatives: R7 gang-split (-6%), R8 in-wave ILP (-10%),
// R9 barrier-free w2-in-LDS (4.2M bank conflicts), R10 wave-local
// recompute (VALU-bound), R11 b2-seed MFMA, R12 b2-in-SGPR.
// NOTE (R1/R2): v_pk_max_i16-as-relu produced NaN twice. Do NOT
// reintroduce (fmax launders transient NaNs; i16-max passes them).
// ===================================================================
__device__ __forceinline__ int kmap(int c, int jj) {
    return 32 * (c >> 2) + 16 * ((c >> 1) & 1) + 4 * (c & 1) + ((jj >> 2) << 3) + (jj & 3);
}

__global__ __launch_bounds__(512, 4)
void crpb_mfma8(const float* __restrict__ gq,   // (512,3)
                const float* __restrict__ gkv,  // (4,512,3)
                const float* __restrict__ W1,   // (3,128)
                const float* __restrict__ b1,   // (128,)
                const float* __restrict__ W2,   // (128,128)
                const float* __restrict__ b2,   // (128,)
                const float* __restrict__ W3,   // (128,4)
                const float* __restrict__ b3,   // (4,)
                float* __restrict__ out)        // (16,512,512)
{
    __shared__ __align__(16) unsigned short ash[2][16 * CH];   // 2 x 16 KB h1 tile
    __shared__ __align__(16) float red[2][4 * 4 * 64];         // 2 x 4 KB [ct][o][pos]
    __shared__ __align__(16) float b2s[128];
    // per-block feature table (one j-row), B-frag word layout.
    __shared__ __align__(16) unsigned fA[512][4];              // 8 KB
    __shared__ __align__(16) unsigned fB[512];                 // 2 KB

    const int tid  = threadIdx.x;
    const int lane = tid & 63;
    const int w    = __builtin_amdgcn_readfirstlane(tid >> 6);  // 0..7
    const int l31  = lane & 31;
    const int lh   = lane >> 5;

    if (tid < 128) b2s[tid] = b2[tid];

    // wave role: ch-tile ct (32 chs), pos-half ph
    const int ct = w & 3;
    const int ph = w >> 2;
    const int pofs = ph * 32 + l31;     // this lane's position within tile

    // persistent zero C-operand (layer-1 and layer-3 MFMAs)
    float16 z16;
    #pragma unroll
    for (int r = 0; r < 16; ++r) z16[r] = 0.0f;

    // ---- layer-1 A-frag for this wave's ch tile (W1 hi/lo + b1 folded) ----
    // lh0 slots: (w0h,w0l),(w0h,w1h),(w1l,w1h),(w2h,w2l)  <-> B: (f0h,f0h),(f0l,f1h),(f1h,f1l),(f2h,f2h)
    // lh1 slots: (w2h,b1h),(b1l,0),0,0                    <-> B: (f2l,1.0),(1.0,0),0,0
    short8 w1f;
    {
        const int ch = ct * 32 + l31;
        const float w0 = W1[ch], w1v = W1[128 + ch], w2v = W1[256 + ch], b1v = b1[ch];
        const float w0h = __uint_as_float(cvt_pk(w0, w0) << 16);
        const float w1h = __uint_as_float(cvt_pk(w1v, w1v) << 16);
        const float w2h = __uint_as_float(cvt_pk(w2v, w2v) << 16);
        const float b1h = __uint_as_float(cvt_pk(b1v, b1v) << 16);
        const float w0l = w0 - w0h, w1l = w1v - w1h, w2l = w2v - w2h, b1l = b1v - b1h;
        unsigned d[4];
        if (lh == 0) {
            d[0] = cvt_pk(w0h, w0l);
            d[1] = cvt_pk(w0h, w1h);
            d[2] = cvt_pk(w1l, w1h);
            d[3] = cvt_pk(w2h, w2l);
        } else {
            d[0] = cvt_pk(w2h, b1h);
            d[1] = cvt_pk(b1l, 0.0f);
            d[2] = 0; d[3] = 0;
        }
        __builtin_memcpy(&w1f, d, 16);
    }

    // ---- W2^T A-frags for this wave's 32 out-chs (32 VGPRs) ----
    short8 a2f[8];
    {
        const int e = ct * 32 + l31;
        #pragma unroll
        for (int ks = 0; ks < 8; ++ks) {
            const int c = 2 * ks + lh;
            unsigned t0[4];
            #pragma unroll
            for (int t = 0; t < 4; ++t) {
                const int d0 = kmap(c, 2 * t), d1 = d0 + 1;
                t0[t] = cvt_pk(W2[d0 * 128 + e], W2[d1 * 128 + e]);
            }
            __builtin_memcpy(&a2f[ks], t0, 16);
        }
    }

    // ---- W3 A-frags: 2 frags cover this wave's 32 chs (8 VGPRs) ----
    short8 w3a[2];
    #pragma unroll
    for (int m2 = 0; m2 < 2; ++m2) {
        unsigned tt[4];
        #pragma unroll
        for (int t = 0; t < 4; ++t) {
            const int chl = ((2 * t) & 3) + 8 * ((2 * t) >> 2) + 4 * lh + 16 * m2;
            const int ch0 = ct * 32 + chl, ch1 = ch0 + 1;
            const float lo = (l31 < 4) ? W3[ch0 * 4 + l31] : 0.0f;
            const float hi = (l31 < 4) ? W3[ch1 * 4 + l31] : 0.0f;
            tt[t] = cvt_pk(lo, hi);
        }
        __builtin_memcpy(&w3a[m2], tt, 16);
    }
    const float b3r = b3[w & 3];   // phase R: waves 0..3, o = w

    // block-constant: one j-row (b, i fixed)
    const int posblock = blockIdx.x * 512;
    const int bb = posblock >> 18;
    const int i  = (posblock >> 9) & 511;
    const float q0 = gq[i * 3 + 0], q1 = gq[i * 3 + 1], q2 = gq[i * 3 + 2];
    const float* kvrow = gkv + (size_t)(bb << 9) * 3;

    // ---- feature precompute: whole j-row, once per block (1 pos/thread) ----
    {
        const int jj = tid;
        const float k0 = kvrow[jj * 3 + 0], k1 = kvrow[jj * 3 + 1], k2 = kvrow[jj * 3 + 2];
        const float c0 = q0 - k0, c1 = q1 - k1, c2 = q2 - k2;
        const float f0 = copysignf(__logf(1.0f + fabsf(c0)), c0);
        const float f1 = copysignf(__logf(1.0f + fabsf(c1)), c1);
        const float f2 = copysignf(__logf(1.0f + fabsf(c2)), c2);
        const unsigned u0 = cvt_pk(f0, f0), u2 = cvt_pk(f2, f2);
        const float f0h = __uint_as_float(u0 << 16);
        const float f1h = __uint_as_float(cvt_pk(f1, f1) << 16);
        const float f2h = __uint_as_float(u2 << 16);
        const float f0l = f0 - f0h, f1l = f1 - f1h, f2l = f2 - f2h;
        fA[jj][0] = u0;                    // (f0h, f0h)
        fA[jj][1] = cvt_pk(f0l, f1);       // (f0l, f1h)
        fA[jj][2] = cvt_pk(f1, f1l);       // (f1h, f1l)
        fA[jj][3] = u2;                    // (f2h, f2h)
        fB[jj]    = cvt_pk(f2l, 1.0f);     // (f2l, 1.0) ; word1 is const
    }
    __syncthreads();   // features + b2s visible to all waves

    // ======== phase A: B-frag from LDS -> layer-1 MFMA -> ash[buf] ========
    auto phaseA = [&](int x, int buf) {
        const int jpos = x * TILE + pofs;
        unsigned d[4];
        if (lh == 0) {
            const uint4v t = *(const uint4v*)&fA[jpos][0];
            d[0] = t[0]; d[1] = t[1]; d[2] = t[2]; d[3] = t[3];
        } else {
            d[0] = fB[jpos];
            d[1] = 0x00003F80u;            // (bf16 1.0, 0) <- picks up b1
            d[2] = 0; d[3] = 0;
        }
        short8 bf; __builtin_memcpy(&bf, d, 16);

        float16 c1r = __builtin_amdgcn_mfma_f32_32x32x16_bf16(w1f, bf, z16, 0, 0, 0);
        unsigned pk0[4], pk1[4];
        #pragma unroll
        for (int t = 0; t < 4; ++t) {
            pk0[t] = cvt_pk(fmaxf(c1r[2 * t], 0.f),     fmaxf(c1r[2 * t + 1], 0.f));
            pk1[t] = cvt_pk(fmaxf(c1r[8 + 2 * t], 0.f), fmaxf(c1r[8 + 2 * t + 1], 0.f));
        }
        short8 v0, v1;
        __builtin_memcpy(&v0, pk0, 16);
        __builtin_memcpy(&v1, pk1, 16);
        *(short8*)&ash[buf][(4 * ct + lh) * CH + pofs * 8]     = v0;   // m=0 octet
        *(short8*)&ash[buf][(4 * ct + 2 + lh) * CH + pofs * 8] = v1;   // m=1 octet
    };

    phaseA(0, 0);
    __syncthreads();   // fences ash[0]

    for (int it = 0; it < ITERS; ++it) {
        const int buf = it & 1;
        const int jb = it * TILE;

        // ======== phase B: layer-2; 8 B-reads feed 8 MFMAs (1 ch tile) ========
        float16 acc;
        #pragma unroll
        for (int qr = 0; qr < 4; ++qr) {
            float4v i0 = *(const float4v*)&b2s[ct * 32 + 8 * qr + 4 * lh];
            #pragma unroll
            for (int t = 0; t < 4; ++t) acc[4 * qr + t] = i0[t];
        }
        const unsigned short* br = &ash[buf][lh * CH + pofs * 8];

        // T5: boost issue priority through the dense MFMA region (R3: -2.7%).
        __builtin_amdgcn_s_setprio(1);
        #pragma unroll
        for (int ks = 0; ks < 8; ++ks) {
            short8 bfrag = *(const short8*)(br + ks * 2 * CH);
            acc = __builtin_amdgcn_mfma_f32_32x32x16_bf16(a2f[ks], bfrag, acc, 0, 0, 0);
        }

        // ======== phase C': in-register relu + layer-3 (2 MFMAs over 32 chs) ========
        {
            unsigned pa0[4], pa1[4];
            #pragma unroll
            for (int t = 0; t < 4; ++t) {
                pa0[t] = cvt_pk(fmaxf(acc[2 * t], 0.f),     fmaxf(acc[2 * t + 1], 0.f));
                pa1[t] = cvt_pk(fmaxf(acc[8 + 2 * t], 0.f), fmaxf(acc[8 + 2 * t + 1], 0.f));
            }
            short8 fa0, fa1;
            __builtin_memcpy(&fa0, pa0, 16); __builtin_memcpy(&fa1, pa1, 16);
            float16 p;
            p = __builtin_amdgcn_mfma_f32_32x32x16_bf16(w3a[0], fa0, z16, 0, 0, 0);
            p = __builtin_amdgcn_mfma_f32_32x32x16_bf16(w3a[1], fa1, p, 0, 0, 0);
            __builtin_amdgcn_s_setprio(0);
            if (lh == 0) {
                #pragma unroll
                for (int o = 0; o < 4; ++o)
                    red[buf][ct * 256 + o * 64 + pofs] = p[o];
            }
        }

        // ======== phase A for next tile (other ash buffer) ========
        if (it != ITERS - 1) phaseA(it + 1, 1 - buf);

        __syncthreads();   // single barrier/tile: fences ash[1-buf] and red[buf]

        // ======== phase R: sum 4 ct-partials + b3, coalesced store (waves 0..3) ========
        if (w < 4) {
            const int o = w, pos = lane;
            const float v = b3r
                          + red[buf][0 * 256 + o * 64 + pos]
                          + red[buf][1 * 256 + o * 64 + pos]
                          + red[buf][2 * 256 + o * 64 + pos]
                          + red[buf][3 * 256 + o * 64 + pos];
            out[((size_t)((bb << 2) + o) << 18) + ((size_t)i << 9) + jb + pos] = v;
        }
    }
}

extern "C" void kernel_launch(void* const* d_in, const int* in_sizes, int n_in,
                              void* d_out, int out_size, void* d_ws, size_t ws_size,
                              hipStream_t stream) {
    const float* gq  = (const float*)d_in[0];
    const float* gkv = (const float*)d_in[1];
    const float* W1  = (const float*)d_in[2];
    const float* b1  = (const float*)d_in[3];
    const float* W2  = (const float*)d_in[4];
    const float* b2  = (const float*)d_in[5];
    const float* W3  = (const float*)d_in[6];
    const float* b3  = (const float*)d_in[7];
    float* out = (float*)d_out;

    crpb_mfma8<<<NBLOCKS, THREADS, 0, stream>>>(gq, gkv, W1, b1, W2, b2, W3, b3, out);
}